// Round 5
// baseline (531.465 us; speedup 1.0000x reference)
//
#include <hip/hip_runtime.h>
#include <hip/hip_bf16.h>

typedef __bf16 bf16;
typedef __bf16 bf16x8 __attribute__((ext_vector_type(8)));
typedef __bf16 bf16x4 __attribute__((ext_vector_type(4)));
typedef float  f32x4  __attribute__((ext_vector_type(4)));
typedef float  f32x16 __attribute__((ext_vector_type(16)));

#define NB 8
#define NS 1024
#define ND 1024
#define NH 16
#define NDK 64
#define NDFF 4096

static __device__ __forceinline__ f32x4 mfma16(bf16x8 a, bf16x8 b, f32x4 c) {
    return __builtin_amdgcn_mfma_f32_16x16x32_bf16(a, b, c, 0, 0, 0);
}
static __device__ __forceinline__ f32x16 mfma32(bf16x8 a, bf16x8 b, f32x16 c) {
    return __builtin_amdgcn_mfma_f32_32x32x16_bf16(a, b, c, 0, 0, 0);
}

#define GLDS(g, l) __builtin_amdgcn_global_load_lds( \
    (const __attribute__((address_space(1))) void*)(g), \
    (__attribute__((address_space(3))) void*)(l), 16, 0, 0)

// fp32 -> bf16 elementwise (n4 = count/4)
__global__ __launch_bounds__(256) void cvt_x(const float* __restrict__ in,
                                             bf16* __restrict__ out, int n4)
{
    int idx = blockIdx.x * 256 + threadIdx.x;
    if (idx >= n4) return;
    float4 v = ((const float4*)in)[idx];
    bf16x4 o = { (bf16)v.x, (bf16)v.y, (bf16)v.z, (bf16)v.w };
    ((bf16x4*)out)[idx] = o;
}

// ---------------------------------------------------------------------------
// Weight prep: fp32 src -> bf16 BT layout [N][K]; fold 0.125 into Wq (exact).
// ---------------------------------------------------------------------------
__global__ __launch_bounds__(256) void prep_transpose(
    const float* __restrict__ Wq, const float* __restrict__ Wk, const float* __restrict__ Wv,
    const float* __restrict__ Wo, const float* __restrict__ W1, const float* __restrict__ W2,
    bf16* __restrict__ wqkvT, bf16* __restrict__ WoT,
    bf16* __restrict__ W1T, bf16* __restrict__ W2T)
{
    __shared__ float T[64][65];
    int bid = blockIdx.x;
    const float* src; bf16* dst; int srcLd, dstLd, tR, tC; bool scale = false;
    if (bid < 768) {                       // Wq/Wk/Wv: per-head [1024x64] -> [64x1024]
        int mat = bid >> 4, ty = bid & 15;
        int h = mat & 15, type = mat >> 4;
        const float* W = (type == 0) ? Wq : (type == 1 ? Wk : Wv);
        src = W + (size_t)h * ND * NDK;
        srcLd = NDK; tR = ty * 64; tC = 0;
        dst = wqkvT + ((size_t)type * 1024 + h * 64) * ND;
        dstLd = ND;
        scale = (type == 0);
    } else if (bid < 1024) {               // Wo [1024x1024] -> WoT
        int b2 = bid - 768; int ty = b2 >> 4, tx = b2 & 15;
        src = Wo; srcLd = ND; tR = ty * 64; tC = tx * 64; dst = WoT; dstLd = ND;
    } else if (bid < 2048) {               // W1 [1024x4096] -> W1T [4096x1024]
        int b2 = bid - 1024; int ty = b2 >> 6, tx = b2 & 63;
        src = W1; srcLd = NDFF; tR = ty * 64; tC = tx * 64; dst = W1T; dstLd = ND;
    } else {                               // W2 [4096x1024] -> W2T [1024x4096]
        int b2 = bid - 2048; int ty = b2 >> 4, tx = b2 & 15;
        src = W2; srcLd = ND; tR = ty * 64; tC = tx * 64; dst = W2T; dstLd = NDFF;
    }
    int t = threadIdx.x;
    int c0 = t & 63, r0 = t >> 6;
    #pragma unroll
    for (int rr = 0; rr < 16; rr++) {
        int row = rr * 4 + r0;
        T[row][c0] = src[(size_t)(tR + row) * srcLd + tC + c0];
    }
    __syncthreads();
    #pragma unroll
    for (int cc = 0; cc < 16; cc++) {
        int col = cc * 4 + r0;
        float v = T[c0][col];
        if (scale) v *= 0.125f;
        dst[(size_t)(tC + col) * dstLd + tR + c0] = (bf16)v;
    }
}

__global__ void prep_bias(const float* __restrict__ bq, const float* __restrict__ bk,
                          const float* __restrict__ bv, float* __restrict__ bqkv)
{
    int n = blockIdx.x * 256 + threadIdx.x;
    if (n >= 3072) return;
    int type = n >> 10, hk = n & 1023;
    const float* bb = (type == 0) ? bq : (type == 1 ? bk : bv);
    float v = bb[hk];
    if (type == 0) v *= 0.125f;
    bqkv[n] = v;
}

// ---------------------------------------------------------------------------
// Core: C[128x128] = A[M,K] * BT[N,K]^T, bf16 in, fp32 acc. 4 waves 2x2.
// 32x32x16 MFMA; global_load_lds(16B) staging; unpadded LDS, XOR-8 swizzle.
// ---------------------------------------------------------------------------
__device__ __forceinline__ void gemm_bt_core(
    const bf16* __restrict__ A, const bf16* __restrict__ BT, int K,
    int rowBase, int colBase, f32x16 (&acc)[2][2], bf16* As, bf16* Bs)
{
    const int tid = threadIdx.x;
    const int lane = tid & 63, wid = tid >> 6;
    const int wr = (wid >> 1) * 64, wc = (wid & 1) * 64;
    const int l31 = lane & 31, lhi = lane >> 5;
    const int srow = wid * 32 + (lane >> 3);
    const int gblk = (lane & 7) ^ ((lane >> 3) & 7);
    const bf16* Arow = A + (size_t)(rowBase + srow) * K + gblk * 8;
    const bf16* Brow = BT + (size_t)(colBase + srow) * K + gblk * 8;
    // fragment col offset per K-16 step ks: block kb = ks*2+lhi, swizzle by row&7 = l31&7
    const int swz = (l31 & 7);
    #pragma unroll
    for (int at = 0; at < 2; at++)
        #pragma unroll
        for (int bt = 0; bt < 2; bt++)
            #pragma unroll
            for (int e = 0; e < 16; e++) acc[at][bt][e] = 0.f;
    for (int k0 = 0; k0 < K; k0 += 64) {
        __syncthreads();
        #pragma unroll
        for (int it = 0; it < 4; it++)
            GLDS(Arow + (size_t)it * 8 * K + k0, As + (wid * 32 + it * 8) * 64);
        #pragma unroll
        for (int it = 0; it < 4; it++)
            GLDS(Brow + (size_t)it * 8 * K + k0, Bs + (wid * 32 + it * 8) * 64);
        __syncthreads();
        #pragma unroll
        for (int ks = 0; ks < 4; ks++) {
            const int co = ((ks * 2 + lhi) ^ swz) * 8;
            bf16x8 af[2], bfr[2];
            af[0]  = *(const bf16x8*)&As[(wr + l31) * 64 + co];
            af[1]  = *(const bf16x8*)&As[(wr + 32 + l31) * 64 + co];
            bfr[0] = *(const bf16x8*)&Bs[(wc + l31) * 64 + co];
            bfr[1] = *(const bf16x8*)&Bs[(wc + 32 + l31) * 64 + co];
            #pragma unroll
            for (int at = 0; at < 2; at++)
                #pragma unroll
                for (int bt = 0; bt < 2; bt++)
                    acc[at][bt] = mfma32(af[at], bfr[bt], acc[at][bt]);
        }
    }
}

// C/D mapping for 32x32: col = base + l31; row = base + (reg&3) + 8*(reg>>2) + 4*lhi
#define CROW(reg) ((reg & 3) + 8 * (reg >> 2) + 4 * lhi)

// G1: xb @ [Wq|Wk|Wv] + bias; Q,K,V all row-major per (b,h).
__global__ __launch_bounds__(256) void g1_qkv(
    const bf16* __restrict__ x, const bf16* __restrict__ wqkvT, const float* __restrict__ bqkv,
    bf16* __restrict__ Q, bf16* __restrict__ Kb, bf16* __restrict__ Vb)
{
    __shared__ bf16 As[128 * 64], Bs[128 * 64];
    f32x16 acc[2][2];
    int rowBase = blockIdx.x * 128, colBase = blockIdx.y * 128;
    gemm_bt_core(x, wqkvT, ND, rowBase, colBase, acc, As, Bs);
    const int tid = threadIdx.x, lane = tid & 63, wid = tid >> 6;
    const int wr = (wid >> 1) * 64, wc = (wid & 1) * 64;
    const int l31 = lane & 31, lhi = lane >> 5;
    #pragma unroll
    for (int bt = 0; bt < 2; bt++) {
        int gcol = colBase + wc + bt * 32 + l31;
        float bias = bqkv[gcol];
        int type = gcol >> 10, h = (gcol >> 6) & 15, kk = gcol & 63;
        bf16* dst = (type == 0) ? Q : (type == 1 ? Kb : Vb);
        #pragma unroll
        for (int at = 0; at < 2; at++) {
            #pragma unroll
            for (int reg = 0; reg < 16; reg++) {
                int grow = rowBase + wr + at * 32 + CROW(reg);
                int b = grow >> 10, s = grow & 1023;
                dst[((size_t)(b * NH + h) * NS + s) * NDK + kk] = (bf16)(acc[at][bt][reg] + bias);
            }
        }
    }
}

// Vb [bh][s][kk] -> Vt [bh][kk][s]  (LDS-tiled transpose)
__global__ __launch_bounds__(256) void vt_trans(
    const bf16* __restrict__ Vb, bf16* __restrict__ Vt)
{
    __shared__ bf16 T[64 * 72];
    int bh = blockIdx.y, s0 = blockIdx.x * 64;
    const bf16* src = Vb + ((size_t)bh * NS + s0) * NDK;
    int tid = threadIdx.x;
    #pragma unroll
    for (int it = 0; it < 2; it++) {
        int g = tid + it * 256;
        int row = g >> 3, c = (g & 7) * 8;
        *(bf16x8*)&T[row * 72 + c] = *(const bf16x8*)&src[row * NDK + c];
    }
    __syncthreads();
    #pragma unroll
    for (int it = 0; it < 2; it++) {
        int g = tid + it * 256;
        int kk = g >> 3, sc = (g & 7) * 8;
        bf16x8 v;
        #pragma unroll
        for (int t = 0; t < 8; t++) v[t] = T[(sc + t) * 72 + kk];
        *(bf16x8*)&Vt[((size_t)bh * NDK + kk) * NS + s0 + sc] = v;
    }
}

// G2: per-key-column coefficients: unmasked (1/sum_i exp(s_ij), 0); masked (0, 1/1024).
__global__ __launch_bounds__(256) void g2_stats(
    const bf16* __restrict__ Q, const bf16* __restrict__ Kb,
    const int* __restrict__ mask, float2* __restrict__ alpha)
{
    __shared__ bf16 Qs[64 * 64];
    int bh = blockIdx.y, b = bh >> 4;
    int jBase = blockIdx.x * 128;
    const bf16* Kp = Kb + (size_t)bh * NS * NDK;
    const bf16* Qp = Q + (size_t)bh * NS * NDK;
    const int tid = threadIdx.x, lane = tid & 63, wid = tid >> 6;
    const int lrow = lane & 15, lq = lane >> 4;
    bf16x8 kf[2][2];
    #pragma unroll
    for (int jt = 0; jt < 2; jt++)
        #pragma unroll
        for (int kh = 0; kh < 2; kh++)
            kf[jt][kh] = *(const bf16x8*)&Kp[(size_t)(jBase + wid * 32 + jt * 16 + lrow) * NDK + kh * 32 + lq * 8];
    const int srow = lane >> 3;
    const int gblk = (lane & 7) ^ srow;
    float Lacc[2][4];
    #pragma unroll
    for (int jt = 0; jt < 2; jt++)
        #pragma unroll
        for (int r = 0; r < 4; r++) Lacc[jt][r] = 0.f;
    f32x4 zz = {0.f, 0.f, 0.f, 0.f};
    for (int i0 = 0; i0 < NS; i0 += 64) {
        __syncthreads();
        #pragma unroll
        for (int it = 0; it < 2; it++)
            GLDS(Qp + (size_t)(i0 + wid * 16 + it * 8 + srow) * NDK + gblk * 8,
                 Qs + (wid * 16 + it * 8) * 64);
        __syncthreads();
        #pragma unroll
        for (int it = 0; it < 4; it++) {
            bf16x8 qb[2];
            #pragma unroll
            for (int kh = 0; kh < 2; kh++)
                qb[kh] = *(const bf16x8*)&Qs[(it * 16 + lrow) * 64 + ((kh * 4 + lq) ^ (lrow & 7)) * 8];
            #pragma unroll
            for (int jt = 0; jt < 2; jt++) {
                f32x4 s = mfma16(kf[jt][0], qb[0], zz);
                s = mfma16(kf[jt][1], qb[1], s);
                #pragma unroll
                for (int r = 0; r < 4; r++) Lacc[jt][r] += __expf(s[r]);
            }
        }
    }
    #pragma unroll
    for (int jt = 0; jt < 2; jt++) {
        #pragma unroll
        for (int r = 0; r < 4; r++) {
            float v = Lacc[jt][r];
            v += __shfl_xor(v, 1); v += __shfl_xor(v, 2);
            v += __shfl_xor(v, 4); v += __shfl_xor(v, 8);
            if (lrow == 0) {
                int j = jBase + wid * 32 + jt * 16 + lq * 4 + r;
                int m = mask[b * NS + j];
                float2 ac;
                ac.x = m ? 1.f / v : 0.f;
                ac.y = m ? 0.f : (1.f / 1024.f);
                alpha[(size_t)bh * NS + j] = ac;
            }
        }
    }
}

// G3: ctx[i][kk] = sum_j (a_j*exp(s_ij)+c_j) * v[j][kk]
__global__ __launch_bounds__(256) void g3_ctx(
    const bf16* __restrict__ Q, const bf16* __restrict__ Kb, const bf16* __restrict__ Vt,
    const float2* __restrict__ alpha, bf16* __restrict__ ctx)
{
    __shared__ bf16 Ks[64 * 64];
    __shared__ bf16 Vs[64 * 64];
    __shared__ bf16 Ps[128 * 64];
    int bh = blockIdx.y, iBase = blockIdx.x * 128;
    int b = bh >> 4, h = bh & 15;
    const bf16* Qp = Q + (size_t)bh * NS * NDK;
    const bf16* Kp = Kb + (size_t)bh * NS * NDK;
    const bf16* Vp = Vt + (size_t)bh * NDK * NS;
    const float2* al = alpha + (size_t)bh * NS;
    const int tid = threadIdx.x, lane = tid & 63, wid = tid >> 6;
    const int lrow = lane & 15, lq = lane >> 4;
    const int wi = wid >> 1, wsub = wid & 1;
    bf16x8 qf[4][2];
    #pragma unroll
    for (int it = 0; it < 4; it++)
        #pragma unroll
        for (int kh = 0; kh < 2; kh++)
            qf[it][kh] = *(const bf16x8*)&Qp[(size_t)(iBase + wi * 64 + it * 16 + lrow) * NDK + kh * 32 + lq * 8];
    const int srow = lane >> 3;
    const int gblk = (lane & 7) ^ srow;
    f32x4 cacc[4][2];
    f32x4 zz = {0.f, 0.f, 0.f, 0.f};
    #pragma unroll
    for (int it = 0; it < 4; it++)
        #pragma unroll
        for (int kt = 0; kt < 2; kt++) cacc[it][kt] = zz;
    for (int j0 = 0; j0 < NS; j0 += 64) {
        __syncthreads();
        #pragma unroll
        for (int it = 0; it < 2; it++)
            GLDS(Kp + (size_t)(j0 + wid * 16 + it * 8 + srow) * NDK + gblk * 8,
                 Ks + (wid * 16 + it * 8) * 64);
        #pragma unroll
        for (int it = 0; it < 2; it++)
            GLDS(Vp + (size_t)(wid * 16 + it * 8 + srow) * NS + j0 + gblk * 8,
                 Vs + (wid * 16 + it * 8) * 64);
        __syncthreads();
        bf16x8 kb[2][2];
        #pragma unroll
        for (int jt = 0; jt < 2; jt++)
            #pragma unroll
            for (int kh = 0; kh < 2; kh++)
                kb[jt][kh] = *(const bf16x8*)&Ks[(wsub * 32 + jt * 16 + lrow) * 64 + ((kh * 4 + lq) ^ (lrow & 7)) * 8];
        float2 ac[2];
        ac[0] = al[j0 + wsub * 32 + lrow];
        ac[1] = al[j0 + wsub * 32 + 16 + lrow];
        #pragma unroll
        for (int it = 0; it < 4; it++) {
            #pragma unroll
            for (int jt = 0; jt < 2; jt++) {
                f32x4 s = mfma16(qf[it][0], kb[jt][0], zz);
                s = mfma16(qf[it][1], kb[jt][1], s);
                #pragma unroll
                for (int r = 0; r < 4; r++) {
                    float p = ac[jt].x * __expf(s[r]) + ac[jt].y;
                    int i = wi * 64 + it * 16 + lq * 4 + r;
                    int j = wsub * 32 + jt * 16 + lrow;
                    Ps[i * 64 + (((j >> 3) ^ (i & 7)) * 8) + (j & 7)] = (bf16)p;
                }
            }
        }
        __syncthreads();
        bf16x8 vb[2][2];
        #pragma unroll
        for (int kt = 0; kt < 2; kt++)
            #pragma unroll
            for (int kh = 0; kh < 2; kh++)
                vb[kt][kh] = *(const bf16x8*)&Vs[(wsub * 32 + kt * 16 + lrow) * 64 + ((kh * 4 + lq) ^ (lrow & 7)) * 8];
        #pragma unroll
        for (int it = 0; it < 4; it++) {
            bf16x8 pa[2];
            #pragma unroll
            for (int kh = 0; kh < 2; kh++)
                pa[kh] = *(const bf16x8*)&Ps[(wi * 64 + it * 16 + lrow) * 64 + ((kh * 4 + lq) ^ (lrow & 7)) * 8];
            #pragma unroll
            for (int kt = 0; kt < 2; kt++) {
                cacc[it][kt] = mfma16(pa[0], vb[kt][0], cacc[it][kt]);
                cacc[it][kt] = mfma16(pa[1], vb[kt][1], cacc[it][kt]);
            }
        }
    }
    #pragma unroll
    for (int kt = 0; kt < 2; kt++) {
        int col = h * NDK + wsub * 32 + kt * 16 + lrow;
        #pragma unroll
        for (int it = 0; it < 4; it++) {
            #pragma unroll
            for (int r = 0; r < 4; r++) {
                int i = iBase + wi * 64 + it * 16 + lq * 4 + r;
                ctx[(size_t)(b * NS + i) * ND + col] = (bf16)cacc[it][kt][r];
            }
        }
    }
}

// G4: t1b = bf16(ctx @ Wo + bo + x)
__global__ __launch_bounds__(256) void g4_proj(
    const bf16* __restrict__ ctx, const bf16* __restrict__ WoT, const float* __restrict__ bo,
    const float* __restrict__ x, bf16* __restrict__ t1b)
{
    __shared__ bf16 As[128 * 64], Bs[128 * 64];
    f32x16 acc[2][2];
    int rowBase = blockIdx.x * 128, colBase = blockIdx.y * 128;
    gemm_bt_core(ctx, WoT, ND, rowBase, colBase, acc, As, Bs);
    const int tid = threadIdx.x, lane = tid & 63, wid = tid >> 6;
    const int wr = (wid >> 1) * 64, wc = (wid & 1) * 64;
    const int l31 = lane & 31, lhi = lane >> 5;
    #pragma unroll
    for (int bt = 0; bt < 2; bt++) {
        int gcol = colBase + wc + bt * 32 + l31;
        float bias = bo[gcol];
        #pragma unroll
        for (int at = 0; at < 2; at++) {
            #pragma unroll
            for (int reg = 0; reg < 16; reg++) {
                int grow = rowBase + wr + at * 32 + CROW(reg);
                float v = acc[at][bt][reg] + bias + x[(size_t)grow * ND + gcol];
                t1b[(size_t)grow * ND + gcol] = (bf16)v;
            }
        }
    }
}

// G5: hb = relu(yb @ W1 + b1)
__global__ __launch_bounds__(256) void g5_ffn1(
    const bf16* __restrict__ y, const bf16* __restrict__ W1T, const float* __restrict__ b1,
    bf16* __restrict__ hb)
{
    __shared__ bf16 As[128 * 64], Bs[128 * 64];
    f32x16 acc[2][2];
    int rowBase = blockIdx.x * 128, colBase = blockIdx.y * 128;
    gemm_bt_core(y, W1T, ND, rowBase, colBase, acc, As, Bs);
    const int tid = threadIdx.x, lane = tid & 63, wid = tid >> 6;
    const int wr = (wid >> 1) * 64, wc = (wid & 1) * 64;
    const int l31 = lane & 31, lhi = lane >> 5;
    #pragma unroll
    for (int bt = 0; bt < 2; bt++) {
        int gcol = colBase + wc + bt * 32 + l31;
        float bias = b1[gcol];
        #pragma unroll
        for (int at = 0; at < 2; at++) {
            #pragma unroll
            for (int reg = 0; reg < 16; reg++) {
                int grow = rowBase + wr + at * 32 + CROW(reg);
                float v = fmaxf(acc[at][bt][reg] + bias, 0.f);
                hb[(size_t)grow * NDFF + gcol] = (bf16)v;
            }
        }
    }
}

// G6: zb = bf16(hb @ W2 + b2 + yb)
__global__ __launch_bounds__(256) void g6_ffn2(
    const bf16* __restrict__ hb, const bf16* __restrict__ W2T, const float* __restrict__ b2,
    const bf16* __restrict__ yb, bf16* __restrict__ zb)
{
    __shared__ bf16 As[128 * 64], Bs[128 * 64];
    f32x16 acc[2][2];
    int rowBase = blockIdx.x * 128, colBase = blockIdx.y * 128;
    gemm_bt_core(hb, W2T, NDFF, rowBase, colBase, acc, As, Bs);
    const int tid = threadIdx.x, lane = tid & 63, wid = tid >> 6;
    const int wr = (wid >> 1) * 64, wc = (wid & 1) * 64;
    const int l31 = lane & 31, lhi = lane >> 5;
    #pragma unroll
    for (int bt = 0; bt < 2; bt++) {
        int gcol = colBase + wc + bt * 32 + l31;
        float bias = b2[gcol];
        #pragma unroll
        for (int at = 0; at < 2; at++) {
            #pragma unroll
            for (int reg = 0; reg < 16; reg++) {
                int grow = rowBase + wr + at * 32 + CROW(reg);
                float v = acc[at][bt][reg] + bias + (float)yb[(size_t)grow * ND + gcol];
                zb[(size_t)grow * ND + gcol] = (bf16)v;
            }
        }
    }
}

// Row LayerNorm over D=1024, bf16 in; writes bf16 (outb) and/or fp32 (outf)
__global__ __launch_bounds__(256) void ln_kernel(
    const bf16* __restrict__ in, bf16* __restrict__ outb, float* __restrict__ outf,
    const float* __restrict__ g, const float* __restrict__ bb)
{
    int row = blockIdx.x, tid = threadIdx.x;
    const bf16* p = in + (size_t)row * ND;
    bf16x4 v4 = *(const bf16x4*)&p[tid * 4];
    float vv[4] = {(float)v4[0], (float)v4[1], (float)v4[2], (float)v4[3]};
    float s = vv[0] + vv[1] + vv[2] + vv[3];
    float q = vv[0]*vv[0] + vv[1]*vv[1] + vv[2]*vv[2] + vv[3]*vv[3];
    #pragma unroll
    for (int m = 1; m < 64; m <<= 1) { s += __shfl_xor(s, m); q += __shfl_xor(q, m); }
    __shared__ float rs[4], rq[4];
    int wid = tid >> 6, lane = tid & 63;
    if (lane == 0) { rs[wid] = s; rq[wid] = q; }
    __syncthreads();
    s = rs[0] + rs[1] + rs[2] + rs[3];
    q = rq[0] + rq[1] + rq[2] + rq[3];
    float mean = s * (1.f / 1024.f);
    float var = q * (1.f / 1024.f) - mean * mean;
    float rstd = 1.f / sqrtf(var + 1e-5f);
    float4 of;
    bf16x4 ob;
    #pragma unroll
    for (int k = 0; k < 4; k++) {
        int col = tid * 4 + k;
        float yv = (vv[k] - mean) * rstd * g[col] + bb[col];
        ((float*)&of)[k] = yv;
        ob[k] = (bf16)yv;
    }
    if (outb) *(bf16x4*)&outb[(size_t)row * ND + tid * 4] = ob;
    if (outf) ((float4*)(outf + (size_t)row * ND))[tid] = of;
}

// ---------------------------------------------------------------------------
extern "C" void kernel_launch(void* const* d_in, const int* in_sizes, int n_in,
                              void* d_out, int out_size, void* d_ws, size_t ws_size,
                              hipStream_t stream)
{
    const float* x    = (const float*)d_in[0];
    const int*   mask = (const int*)d_in[1];
    const float* Wq   = (const float*)d_in[2];
    const float* bq   = (const float*)d_in[3];
    const float* Wk   = (const float*)d_in[4];
    const float* bk   = (const float*)d_in[5];
    const float* Wv   = (const float*)d_in[6];
    const float* bv   = (const float*)d_in[7];
    const float* Wo   = (const float*)d_in[8];
    const float* bo   = (const float*)d_in[9];
    const float* ga   = (const float*)d_in[10];
    const float* ba   = (const float*)d_in[11];
    const float* W1   = (const float*)d_in[12];
    const float* b1   = (const float*)d_in[13];
    const float* W2   = (const float*)d_in[14];
    const float* b2   = (const float*)d_in[15];
    const float* gf   = (const float*)d_in[16];
    const float* bfb  = (const float*)d_in[17];

    size_t off = 0;
    auto alloc = [&](size_t n) { char* p = (char*)d_ws + off; off += (n + 255) & ~(size_t)255; return (void*)p; };
    bf16*   wqkvT = (bf16*)  alloc((size_t)3072 * 1024 * 2);           // 6 MB
    bf16*   WoT   = (bf16*)  alloc((size_t)1024 * 1024 * 2);           // 2 MB
    bf16*   W1T   = (bf16*)  alloc((size_t)4096 * 1024 * 2);           // 8 MB
    bf16*   W2T   = (bf16*)  alloc((size_t)1024 * 4096 * 2);           // 8 MB
    float*  bqkv  = (float*) alloc(3072 * 4);
    float2* alpha = (float2*)alloc((size_t)NB * NH * NS * 8);          // 1 MB
    bf16*   xb    = (bf16*)  alloc((size_t)8192 * 1024 * 2);           // 16 MB
    // 64 MB union: Qb|Kb|Vt|ctx live until g4; hb (g5/g6) aliases the whole block
    bf16*   ub    = (bf16*)  alloc((size_t)8192 * 4096 * 2);           // 64 MB
    bf16*   Qb    = ub;
    bf16*   Kb    = ub + (size_t)8192 * 1024;
    bf16*   Vt    = ub + (size_t)2 * 8192 * 1024;
    bf16*   ctx   = ub + (size_t)3 * 8192 * 1024;
    bf16*   hb    = ub;
    // 16 MB region shared by Vb (g1->vt_trans), t1b (g4->ln1), zb (g6->ln2)
    bf16*   t1b   = (bf16*)  alloc((size_t)8192 * 1024 * 2);           // 16 MB
    bf16*   Vb    = t1b;
    bf16*   zb    = t1b;
    bf16*   yb    = (bf16*)  alloc((size_t)8192 * 1024 * 2);           // 16 MB

    cvt_x<<<8192, 256, 0, stream>>>(x, xb, 8192 * 1024 / 4);
    prep_transpose<<<3072, 256, 0, stream>>>(Wq, Wk, Wv, Wo, W1, W2, wqkvT, WoT, W1T, W2T);
    prep_bias<<<12, 256, 0, stream>>>(bq, bk, bv, bqkv);
    g1_qkv<<<dim3(64, 24), 256, 0, stream>>>(xb, wqkvT, bqkv, Qb, Kb, Vb);
    vt_trans<<<dim3(16, 128), 256, 0, stream>>>(Vb, Vt);
    g2_stats<<<dim3(8, 128), 256, 0, stream>>>(Qb, Kb, mask, alpha);
    g3_ctx<<<dim3(8, 128), 256, 0, stream>>>(Qb, Kb, Vt, alpha, ctx);
    g4_proj<<<dim3(64, 8), 256, 0, stream>>>(ctx, WoT, bo, x, t1b);
    ln_kernel<<<8192, 256, 0, stream>>>(t1b, yb, nullptr, ga, ba);
    g5_ffn1<<<dim3(64, 32), 256, 0, stream>>>(yb, W1T, b1, hb);
    g6_ffn2<<<dim3(64, 8), 256, 0, stream>>>(hb, W2T, b2, yb, zb);
    ln_kernel<<<8192, 256, 0, stream>>>(zb, nullptr, (float*)d_out, gf, bfb);
}

// Round 6
// 501.911 us; speedup vs baseline: 1.0589x; 1.0589x over previous
//
#include <hip/hip_runtime.h>
#include <hip/hip_bf16.h>

typedef __bf16 bf16;
typedef __bf16 bf16x8 __attribute__((ext_vector_type(8)));
typedef __bf16 bf16x4 __attribute__((ext_vector_type(4)));
typedef float  f32x4  __attribute__((ext_vector_type(4)));

#define NB 8
#define NS 1024
#define ND 1024
#define NH 16
#define NDK 64
#define NDFF 4096

static __device__ __forceinline__ f32x4 mfma16(bf16x8 a, bf16x8 b, f32x4 c) {
    return __builtin_amdgcn_mfma_f32_16x16x32_bf16(a, b, c, 0, 0, 0);
}

#define GLDS(g, l) __builtin_amdgcn_global_load_lds( \
    (const __attribute__((address_space(1))) void*)(g), \
    (__attribute__((address_space(3))) void*)(l), 16, 0, 0)

// fp32 -> bf16 elementwise (n4 = count/4)
__global__ __launch_bounds__(256) void cvt_x(const float* __restrict__ in,
                                             bf16* __restrict__ out, int n4)
{
    int idx = blockIdx.x * 256 + threadIdx.x;
    if (idx >= n4) return;
    float4 v = ((const float4*)in)[idx];
    bf16x4 o = { (bf16)v.x, (bf16)v.y, (bf16)v.z, (bf16)v.w };
    ((bf16x4*)out)[idx] = o;
}

// ---------------------------------------------------------------------------
// Weight prep: fp32 src -> bf16 BT layout [N][K]; fold 0.125 into Wq (exact).
// ---------------------------------------------------------------------------
__global__ __launch_bounds__(256) void prep_transpose(
    const float* __restrict__ Wq, const float* __restrict__ Wk, const float* __restrict__ Wv,
    const float* __restrict__ Wo, const float* __restrict__ W1, const float* __restrict__ W2,
    bf16* __restrict__ wqkvT, bf16* __restrict__ WoT,
    bf16* __restrict__ W1T, bf16* __restrict__ W2T)
{
    __shared__ float T[64][65];
    int bid = blockIdx.x;
    const float* src; bf16* dst; int srcLd, dstLd, tR, tC; bool scale = false;
    if (bid < 768) {                       // Wq/Wk/Wv: per-head [1024x64] -> [64x1024]
        int mat = bid >> 4, ty = bid & 15;
        int h = mat & 15, type = mat >> 4;
        const float* W = (type == 0) ? Wq : (type == 1 ? Wk : Wv);
        src = W + (size_t)h * ND * NDK;
        srcLd = NDK; tR = ty * 64; tC = 0;
        dst = wqkvT + ((size_t)type * 1024 + h * 64) * ND;
        dstLd = ND;
        scale = (type == 0);
    } else if (bid < 1024) {               // Wo [1024x1024] -> WoT
        int b2 = bid - 768; int ty = b2 >> 4, tx = b2 & 15;
        src = Wo; srcLd = ND; tR = ty * 64; tC = tx * 64; dst = WoT; dstLd = ND;
    } else if (bid < 2048) {               // W1 [1024x4096] -> W1T [4096x1024]
        int b2 = bid - 1024; int ty = b2 >> 6, tx = b2 & 63;
        src = W1; srcLd = NDFF; tR = ty * 64; tC = tx * 64; dst = W1T; dstLd = ND;
    } else {                               // W2 [4096x1024] -> W2T [1024x4096]
        int b2 = bid - 2048; int ty = b2 >> 4, tx = b2 & 15;
        src = W2; srcLd = ND; tR = ty * 64; tC = tx * 64; dst = W2T; dstLd = NDFF;
    }
    int t = threadIdx.x;
    int c0 = t & 63, r0 = t >> 6;
    #pragma unroll
    for (int rr = 0; rr < 16; rr++) {
        int row = rr * 4 + r0;
        T[row][c0] = src[(size_t)(tR + row) * srcLd + tC + c0];
    }
    __syncthreads();
    #pragma unroll
    for (int cc = 0; cc < 16; cc++) {
        int col = cc * 4 + r0;
        float v = T[c0][col];
        if (scale) v *= 0.125f;
        dst[(size_t)(tC + col) * dstLd + tR + c0] = (bf16)v;
    }
}

__global__ void prep_bias(const float* __restrict__ bq, const float* __restrict__ bk,
                          const float* __restrict__ bv, float* __restrict__ bqkv)
{
    int n = blockIdx.x * 256 + threadIdx.x;
    if (n >= 3072) return;
    int type = n >> 10, hk = n & 1023;
    const float* bb = (type == 0) ? bq : (type == 1 ? bk : bv);
    float v = bb[hk];
    if (type == 0) v *= 0.125f;
    bqkv[n] = v;
}

// ---------------------------------------------------------------------------
// Core: C[128x128] = A[M,K] * BT[N,K]^T, bf16 in, fp32 acc. 4 waves 2x2.
// 16x16x32 MFMA; global_load_lds(16B) staging; unpadded LDS, XOR-8 swizzle.
// (verified 0 bank conflicts; 32x32 variant regressed w/ 8.4M conflicts)
// ---------------------------------------------------------------------------
__device__ __forceinline__ void gemm_bt_core(
    const bf16* __restrict__ A, const bf16* __restrict__ BT, int K,
    int rowBase, int colBase, f32x4 (&acc)[4][4], bf16* As, bf16* Bs)
{
    const int tid = threadIdx.x;
    const int lane = tid & 63, wid = tid >> 6;
    const int wr = (wid >> 1) * 64, wc = (wid & 1) * 64;
    const int lrow = lane & 15, lq = lane >> 4;
    const int srow = wid * 32 + (lane >> 3);
    const int gblk = (lane & 7) ^ ((lane >> 3) & 7);
    const bf16* Arow = A + (size_t)(rowBase + srow) * K + gblk * 8;
    const bf16* Brow = BT + (size_t)(colBase + srow) * K + gblk * 8;
    const int co0 = ((lq) ^ (lrow & 7)) * 8;
    const int co1 = ((4 + lq) ^ (lrow & 7)) * 8;
    f32x4 zz = {0.f, 0.f, 0.f, 0.f};
    #pragma unroll
    for (int i = 0; i < 4; i++)
        #pragma unroll
        for (int j = 0; j < 4; j++) acc[i][j] = zz;
    for (int k0 = 0; k0 < K; k0 += 64) {
        __syncthreads();
        #pragma unroll
        for (int it = 0; it < 4; it++)
            GLDS(Arow + (size_t)it * 8 * K + k0, As + (wid * 32 + it * 8) * 64);
        #pragma unroll
        for (int it = 0; it < 4; it++)
            GLDS(Brow + (size_t)it * 8 * K + k0, Bs + (wid * 32 + it * 8) * 64);
        __syncthreads();
        #pragma unroll
        for (int kh = 0; kh < 2; kh++) {
            const int co = kh ? co1 : co0;
            bf16x8 af[4], bfr[4];
            #pragma unroll
            for (int tt = 0; tt < 4; tt++) {
                af[tt]  = *(const bf16x8*)&As[(wr + tt * 16 + lrow) * 64 + co];
                bfr[tt] = *(const bf16x8*)&Bs[(wc + tt * 16 + lrow) * 64 + co];
            }
            #pragma unroll
            for (int i = 0; i < 4; i++)
                #pragma unroll
                for (int j = 0; j < 4; j++)
                    acc[i][j] = mfma16(af[i], bfr[j], acc[i][j]);
        }
    }
}

// G1: xb @ [Wq|Wk|Wv] + bias; Q,K,V all row-major per (b,h).
__global__ __launch_bounds__(256) void g1_qkv(
    const bf16* __restrict__ x, const bf16* __restrict__ wqkvT, const float* __restrict__ bqkv,
    bf16* __restrict__ Q, bf16* __restrict__ Kb, bf16* __restrict__ Vb)
{
    __shared__ bf16 As[128 * 64], Bs[128 * 64];
    f32x4 acc[4][4];
    int rowBase = blockIdx.x * 128, colBase = blockIdx.y * 128;
    gemm_bt_core(x, wqkvT, ND, rowBase, colBase, acc, As, Bs);
    const int tid = threadIdx.x, lane = tid & 63, wid = tid >> 6;
    const int wr = (wid >> 1) * 64, wc = (wid & 1) * 64, lrow = lane & 15, lq = lane >> 4;
    #pragma unroll
    for (int j = 0; j < 4; j++) {
        int gcol = colBase + wc + j * 16 + lrow;
        float bias = bqkv[gcol];
        int type = gcol >> 10, h = (gcol >> 6) & 15, kk = gcol & 63;
        bf16* dst = (type == 0) ? Q : (type == 1 ? Kb : Vb);
        #pragma unroll
        for (int i = 0; i < 4; i++) {
            #pragma unroll
            for (int r = 0; r < 4; r++) {
                int grow = rowBase + wr + i * 16 + lq * 4 + r;
                int b = grow >> 10, s = grow & 1023;
                dst[((size_t)(b * NH + h) * NS + s) * NDK + kk] = (bf16)(acc[i][j][r] + bias);
            }
        }
    }
}

// Vb [bh][s][kk] -> Vt [bh][kk][s]  (LDS-tiled transpose)
__global__ __launch_bounds__(256) void vt_trans(
    const bf16* __restrict__ Vb, bf16* __restrict__ Vt)
{
    __shared__ bf16 T[64 * 72];
    int bh = blockIdx.y, s0 = blockIdx.x * 64;
    const bf16* src = Vb + ((size_t)bh * NS + s0) * NDK;
    int tid = threadIdx.x;
    #pragma unroll
    for (int it = 0; it < 2; it++) {
        int g = tid + it * 256;
        int row = g >> 3, c = (g & 7) * 8;
        *(bf16x8*)&T[row * 72 + c] = *(const bf16x8*)&src[row * NDK + c];
    }
    __syncthreads();
    #pragma unroll
    for (int it = 0; it < 2; it++) {
        int g = tid + it * 256;
        int kk = g >> 3, sc = (g & 7) * 8;
        bf16x8 v;
        #pragma unroll
        for (int t = 0; t < 8; t++) v[t] = T[(sc + t) * 72 + kk];
        *(bf16x8*)&Vt[((size_t)bh * NDK + kk) * NS + s0 + sc] = v;
    }
}

// G2: per-key-column coefficients: unmasked (1/sum_i exp(s_ij), 0); masked (0, 1/1024).
// j-tile 128/block, K A-frags in registers, i staged 128/step via GLDS.
__global__ __launch_bounds__(256) void g2_stats(
    const bf16* __restrict__ Q, const bf16* __restrict__ Kb,
    const int* __restrict__ mask, float2* __restrict__ alpha)
{
    __shared__ bf16 Qs[128 * 64];
    int bh = blockIdx.y, b = bh >> 4;
    int jBase = blockIdx.x * 128;
    const bf16* Kp = Kb + (size_t)bh * NS * NDK;
    const bf16* Qp = Q + (size_t)bh * NS * NDK;
    const int tid = threadIdx.x, lane = tid & 63, wid = tid >> 6;
    const int lrow = lane & 15, lq = lane >> 4;
    bf16x8 kf[2][2];
    #pragma unroll
    for (int jt = 0; jt < 2; jt++)
        #pragma unroll
        for (int kh = 0; kh < 2; kh++)
            kf[jt][kh] = *(const bf16x8*)&Kp[(size_t)(jBase + wid * 32 + jt * 16 + lrow) * NDK + kh * 32 + lq * 8];
    const int srow = lane >> 3;
    const int gblk = (lane & 7) ^ srow;
    float Lacc[2][4];
    #pragma unroll
    for (int jt = 0; jt < 2; jt++)
        #pragma unroll
        for (int r = 0; r < 4; r++) Lacc[jt][r] = 0.f;
    f32x4 zz = {0.f, 0.f, 0.f, 0.f};
    for (int i0 = 0; i0 < NS; i0 += 128) {
        __syncthreads();
        #pragma unroll
        for (int it = 0; it < 4; it++)
            GLDS(Qp + (size_t)(i0 + wid * 32 + it * 8 + srow) * NDK + gblk * 8,
                 Qs + (wid * 32 + it * 8) * 64);
        __syncthreads();
        #pragma unroll
        for (int it = 0; it < 8; it++) {
            bf16x8 qb[2];
            #pragma unroll
            for (int kh = 0; kh < 2; kh++)
                qb[kh] = *(const bf16x8*)&Qs[(it * 16 + lrow) * 64 + ((kh * 4 + lq) ^ (lrow & 7)) * 8];
            #pragma unroll
            for (int jt = 0; jt < 2; jt++) {
                f32x4 s = mfma16(kf[jt][0], qb[0], zz);
                s = mfma16(kf[jt][1], qb[1], s);
                #pragma unroll
                for (int r = 0; r < 4; r++) Lacc[jt][r] += __expf(s[r]);
            }
        }
    }
    #pragma unroll
    for (int jt = 0; jt < 2; jt++) {
        #pragma unroll
        for (int r = 0; r < 4; r++) {
            float v = Lacc[jt][r];
            v += __shfl_xor(v, 1); v += __shfl_xor(v, 2);
            v += __shfl_xor(v, 4); v += __shfl_xor(v, 8);
            if (lrow == 0) {
                int j = jBase + wid * 32 + jt * 16 + lq * 4 + r;
                int m = mask[b * NS + j];
                float2 ac;
                ac.x = m ? 1.f / v : 0.f;
                ac.y = m ? 0.f : (1.f / 1024.f);
                alpha[(size_t)bh * NS + j] = ac;
            }
        }
    }
}

// G3: ctx[i][kk] = sum_j (a_j*exp(s_ij)+c_j) * v[j][kk]
// i-tile 256/block; each wave owns 64 rows end-to-end -> wave-private P,
// no S->PV barrier. S computed transposed (C row = j) so P writes pack b64.
__global__ __launch_bounds__(256) void g3_ctx(
    const bf16* __restrict__ Q, const bf16* __restrict__ Kb, const bf16* __restrict__ Vt,
    const float2* __restrict__ alpha, bf16* __restrict__ ctx)
{
    __shared__ bf16 Ks[64 * 64];       // 8 KB
    __shared__ bf16 Vs[64 * 64];       // 8 KB
    __shared__ bf16 Ps[4 * 64 * 64];   // 32 KB, per-wave 8KB, XOR-swizzled
    int bh = blockIdx.y, iBase = blockIdx.x * 256;
    int b = bh >> 4, h = bh & 15;
    const bf16* Qp = Q + (size_t)bh * NS * NDK;
    const bf16* Kp = Kb + (size_t)bh * NS * NDK;
    const bf16* Vp = Vt + (size_t)bh * NDK * NS;
    const float2* al = alpha + (size_t)bh * NS;
    const int tid = threadIdx.x, lane = tid & 63, wid = tid >> 6;
    const int lrow = lane & 15, lq = lane >> 4;
    const int iw = iBase + wid * 64;
    // Q B-frags in registers: rows iw + it*16 + lrow
    bf16x8 qf[4][2];
    #pragma unroll
    for (int it = 0; it < 4; it++)
        #pragma unroll
        for (int kh = 0; kh < 2; kh++)
            qf[it][kh] = *(const bf16x8*)&Qp[(size_t)(iw + it * 16 + lrow) * NDK + kh * 32 + lq * 8];
    const int srow = lane >> 3;
    const int gblk = (lane & 7) ^ srow;
    f32x4 cacc[4][4];
    f32x4 zz = {0.f, 0.f, 0.f, 0.f};
    #pragma unroll
    for (int it = 0; it < 4; it++)
        #pragma unroll
        for (int kt = 0; kt < 4; kt++) cacc[it][kt] = zz;
    bf16* Pw = Ps + wid * 64 * 64;
    for (int j0 = 0; j0 < NS; j0 += 64) {
        __syncthreads();
        #pragma unroll
        for (int it = 0; it < 2; it++)
            GLDS(Kp + (size_t)(j0 + wid * 16 + it * 8 + srow) * NDK + gblk * 8,
                 Ks + (wid * 16 + it * 8) * 64);
        #pragma unroll
        for (int it = 0; it < 2; it++)
            GLDS(Vp + (size_t)(wid * 16 + it * 8 + srow) * NS + j0 + gblk * 8,
                 Vs + (wid * 16 + it * 8) * 64);
        __syncthreads();
        // S phase (transposed): A = K rows j, B = Q rows i.
        bf16x8 kb[4][2];
        #pragma unroll
        for (int jt = 0; jt < 4; jt++)
            #pragma unroll
            for (int kh = 0; kh < 2; kh++)
                kb[jt][kh] = *(const bf16x8*)&Ks[(jt * 16 + lrow) * 64 + ((kh * 4 + lq) ^ (lrow & 7)) * 8];
        #pragma unroll
        for (int jt = 0; jt < 4; jt++) {
            float2 acj[4];
            #pragma unroll
            for (int r = 0; r < 4; r++) acj[r] = al[j0 + jt * 16 + lq * 4 + r];
            #pragma unroll
            for (int it = 0; it < 4; it++) {
                f32x4 s = mfma16(kb[jt][0], qf[it][0], zz);
                s = mfma16(kb[jt][1], qf[it][1], s);
                // C: row = j = jt*16 + lq*4 + r, col = i = it*16 + lrow
                bf16x4 pv;
                #pragma unroll
                for (int r = 0; r < 4; r++)
                    pv[r] = (bf16)(acj[r].x * __expf(s[r]) + acj[r].y);
                int i = it * 16 + lrow;
                int jb = jt * 2 + (lq >> 1);       // 8-elem block index of j
                *(bf16x4*)&Pw[i * 64 + ((jb ^ (i & 7)) * 8) + (lq & 1) * 4] = pv;
            }
        }
        // no barrier: Pw is wave-private; compiler orders ds_write->ds_read
        bf16x8 vb[4][2];
        #pragma unroll
        for (int kt = 0; kt < 4; kt++)
            #pragma unroll
            for (int kh = 0; kh < 2; kh++)
                vb[kt][kh] = *(const bf16x8*)&Vs[(kt * 16 + lrow) * 64 + ((kh * 4 + lq) ^ (lrow & 7)) * 8];
        #pragma unroll
        for (int it = 0; it < 4; it++) {
            bf16x8 pa[2];
            #pragma unroll
            for (int kh = 0; kh < 2; kh++)
                pa[kh] = *(const bf16x8*)&Pw[(it * 16 + lrow) * 64 + ((kh * 4 + lq) ^ (lrow & 7)) * 8];
            #pragma unroll
            for (int kt = 0; kt < 4; kt++) {
                cacc[it][kt] = mfma16(pa[0], vb[kt][0], cacc[it][kt]);
                cacc[it][kt] = mfma16(pa[1], vb[kt][1], cacc[it][kt]);
            }
        }
    }
    #pragma unroll
    for (int kt = 0; kt < 4; kt++) {
        int col = h * NDK + kt * 16 + lrow;
        #pragma unroll
        for (int it = 0; it < 4; it++) {
            #pragma unroll
            for (int r = 0; r < 4; r++) {
                int i = iw + it * 16 + lq * 4 + r;
                ctx[(size_t)(b * NS + i) * ND + col] = (bf16)cacc[it][kt][r];
            }
        }
    }
}

// G4: t1b = bf16(ctx @ Wo + bo + xb)
__global__ __launch_bounds__(256) void g4_proj(
    const bf16* __restrict__ ctx, const bf16* __restrict__ WoT, const float* __restrict__ bo,
    const bf16* __restrict__ xb, bf16* __restrict__ t1b)
{
    __shared__ bf16 As[128 * 64], Bs[128 * 64];
    f32x4 acc[4][4];
    int rowBase = blockIdx.x * 128, colBase = blockIdx.y * 128;
    gemm_bt_core(ctx, WoT, ND, rowBase, colBase, acc, As, Bs);
    const int tid = threadIdx.x, lane = tid & 63, wid = tid >> 6;
    const int wr = (wid >> 1) * 64, wc = (wid & 1) * 64, lrow = lane & 15, lq = lane >> 4;
    #pragma unroll
    for (int j = 0; j < 4; j++) {
        int gcol = colBase + wc + j * 16 + lrow;
        float bias = bo[gcol];
        #pragma unroll
        for (int i = 0; i < 4; i++) {
            #pragma unroll
            for (int r = 0; r < 4; r++) {
                int grow = rowBase + wr + i * 16 + lq * 4 + r;
                float v = acc[i][j][r] + bias + (float)xb[(size_t)grow * ND + gcol];
                t1b[(size_t)grow * ND + gcol] = (bf16)v;
            }
        }
    }
}

// G5: hb = relu(yb @ W1 + b1)
__global__ __launch_bounds__(256) void g5_ffn1(
    const bf16* __restrict__ y, const bf16* __restrict__ W1T, const float* __restrict__ b1,
    bf16* __restrict__ hb)
{
    __shared__ bf16 As[128 * 64], Bs[128 * 64];
    f32x4 acc[4][4];
    int rowBase = blockIdx.x * 128, colBase = blockIdx.y * 128;
    gemm_bt_core(y, W1T, ND, rowBase, colBase, acc, As, Bs);
    const int tid = threadIdx.x, lane = tid & 63, wid = tid >> 6;
    const int wr = (wid >> 1) * 64, wc = (wid & 1) * 64, lrow = lane & 15, lq = lane >> 4;
    #pragma unroll
    for (int j = 0; j < 4; j++) {
        int gcol = colBase + wc + j * 16 + lrow;
        float bias = b1[gcol];
        #pragma unroll
        for (int i = 0; i < 4; i++) {
            #pragma unroll
            for (int r = 0; r < 4; r++) {
                int grow = rowBase + wr + i * 16 + lq * 4 + r;
                float v = fmaxf(acc[i][j][r] + bias, 0.f);
                hb[(size_t)grow * NDFF + gcol] = (bf16)v;
            }
        }
    }
}

// G6: zb = bf16(hb @ W2 + b2 + yb)
__global__ __launch_bounds__(256) void g6_ffn2(
    const bf16* __restrict__ hb, const bf16* __restrict__ W2T, const float* __restrict__ b2,
    const bf16* __restrict__ yb, bf16* __restrict__ zb)
{
    __shared__ bf16 As[128 * 64], Bs[128 * 64];
    f32x4 acc[4][4];
    int rowBase = blockIdx.x * 128, colBase = blockIdx.y * 128;
    gemm_bt_core(hb, W2T, NDFF, rowBase, colBase, acc, As, Bs);
    const int tid = threadIdx.x, lane = tid & 63, wid = tid >> 6;
    const int wr = (wid >> 1) * 64, wc = (wid & 1) * 64, lrow = lane & 15, lq = lane >> 4;
    #pragma unroll
    for (int j = 0; j < 4; j++) {
        int gcol = colBase + wc + j * 16 + lrow;
        float bias = b2[gcol];
        #pragma unroll
        for (int i = 0; i < 4; i++) {
            #pragma unroll
            for (int r = 0; r < 4; r++) {
                int grow = rowBase + wr + i * 16 + lq * 4 + r;
                float v = acc[i][j][r] + bias + (float)yb[(size_t)grow * ND + gcol];
                zb[(size_t)grow * ND + gcol] = (bf16)v;
            }
        }
    }
}

// Row LayerNorm over D=1024, bf16 in; writes bf16 (outb) and/or fp32 (outf)
__global__ __launch_bounds__(256) void ln_kernel(
    const bf16* __restrict__ in, bf16* __restrict__ outb, float* __restrict__ outf,
    const float* __restrict__ g, const float* __restrict__ bb)
{
    int row = blockIdx.x, tid = threadIdx.x;
    const bf16* p = in + (size_t)row * ND;
    bf16x4 v4 = *(const bf16x4*)&p[tid * 4];
    float vv[4] = {(float)v4[0], (float)v4[1], (float)v4[2], (float)v4[3]};
    float s = vv[0] + vv[1] + vv[2] + vv[3];
    float q = vv[0]*vv[0] + vv[1]*vv[1] + vv[2]*vv[2] + vv[3]*vv[3];
    #pragma unroll
    for (int m = 1; m < 64; m <<= 1) { s += __shfl_xor(s, m); q += __shfl_xor(q, m); }
    __shared__ float rs[4], rq[4];
    int wid = tid >> 6, lane = tid & 63;
    if (lane == 0) { rs[wid] = s; rq[wid] = q; }
    __syncthreads();
    s = rs[0] + rs[1] + rs[2] + rs[3];
    q = rq[0] + rq[1] + rq[2] + rq[3];
    float mean = s * (1.f / 1024.f);
    float var = q * (1.f / 1024.f) - mean * mean;
    float rstd = 1.f / sqrtf(var + 1e-5f);
    float4 of;
    bf16x4 ob;
    #pragma unroll
    for (int k = 0; k < 4; k++) {
        int col = tid * 4 + k;
        float yv = (vv[k] - mean) * rstd * g[col] + bb[col];
        ((float*)&of)[k] = yv;
        ob[k] = (bf16)yv;
    }
    if (outb) *(bf16x4*)&outb[(size_t)row * ND + tid * 4] = ob;
    if (outf) ((float4*)(outf + (size_t)row * ND))[tid] = of;
}

// ---------------------------------------------------------------------------
extern "C" void kernel_launch(void* const* d_in, const int* in_sizes, int n_in,
                              void* d_out, int out_size, void* d_ws, size_t ws_size,
                              hipStream_t stream)
{
    const float* x    = (const float*)d_in[0];
    const int*   mask = (const int*)d_in[1];
    const float* Wq   = (const float*)d_in[2];
    const float* bq   = (const float*)d_in[3];
    const float* Wk   = (const float*)d_in[4];
    const float* bk   = (const float*)d_in[5];
    const float* Wv   = (const float*)d_in[6];
    const float* bv   = (const float*)d_in[7];
    const float* Wo   = (const float*)d_in[8];
    const float* bo   = (const float*)d_in[9];
    const float* ga   = (const float*)d_in[10];
    const float* ba   = (const float*)d_in[11];
    const float* W1   = (const float*)d_in[12];
    const float* b1   = (const float*)d_in[13];
    const float* W2   = (const float*)d_in[14];
    const float* b2   = (const float*)d_in[15];
    const float* gf   = (const float*)d_in[16];
    const float* bfb  = (const float*)d_in[17];

    size_t off = 0;
    auto alloc = [&](size_t n) { char* p = (char*)d_ws + off; off += (n + 255) & ~(size_t)255; return (void*)p; };
    bf16*   wqkvT = (bf16*)  alloc((size_t)3072 * 1024 * 2);           // 6 MB
    bf16*   WoT   = (bf16*)  alloc((size_t)1024 * 1024 * 2);           // 2 MB
    bf16*   W1T   = (bf16*)  alloc((size_t)4096 * 1024 * 2);           // 8 MB
    bf16*   W2T   = (bf16*)  alloc((size_t)1024 * 4096 * 2);           // 8 MB
    float*  bqkv  = (float*) alloc(3072 * 4);
    float2* alpha = (float2*)alloc((size_t)NB * NH * NS * 8);          // 1 MB
    bf16*   xb    = (bf16*)  alloc((size_t)8192 * 1024 * 2);           // 16 MB
    // 64 MB union: Qb|Kb|Vt|ctx live until g4; hb (g5/g6) aliases the whole block
    bf16*   ub    = (bf16*)  alloc((size_t)8192 * 4096 * 2);           // 64 MB
    bf16*   Qb    = ub;
    bf16*   Kb    = ub + (size_t)8192 * 1024;
    bf16*   Vt    = ub + (size_t)2 * 8192 * 1024;
    bf16*   ctx   = ub + (size_t)3 * 8192 * 1024;
    bf16*   hb    = ub;
    // 16 MB region shared by Vb (g1->vt_trans), t1b (g4->ln1), zb (g6->ln2)
    bf16*   t1b   = (bf16*)  alloc((size_t)8192 * 1024 * 2);           // 16 MB
    bf16*   Vb    = t1b;
    bf16*   zb    = t1b;
    bf16*   yb    = (bf16*)  alloc((size_t)8192 * 1024 * 2);           // 16 MB

    cvt_x<<<8192, 256, 0, stream>>>(x, xb, 8192 * 1024 / 4);
    prep_transpose<<<3072, 256, 0, stream>>>(Wq, Wk, Wv, Wo, W1, W2, wqkvT, WoT, W1T, W2T);
    prep_bias<<<12, 256, 0, stream>>>(bq, bk, bv, bqkv);
    g1_qkv<<<dim3(64, 24), 256, 0, stream>>>(xb, wqkvT, bqkv, Qb, Kb, Vb);
    vt_trans<<<dim3(16, 128), 256, 0, stream>>>(Vb, Vt);
    g2_stats<<<dim3(8, 128), 256, 0, stream>>>(Qb, Kb, mask, alpha);
    g3_ctx<<<dim3(4, 128), 256, 0, stream>>>(Qb, Kb, Vt, alpha, ctx);
    g4_proj<<<dim3(64, 8), 256, 0, stream>>>(ctx, WoT, bo, xb, t1b);
    ln_kernel<<<8192, 256, 0, stream>>>(t1b, yb, nullptr, ga, ba);
    g5_ffn1<<<dim3(64, 32), 256, 0, stream>>>(yb, W1T, b1, hb);
    g6_ffn2<<<dim3(64, 8), 256, 0, stream>>>(hb, W2T, b2, yb, zb);
    ln_kernel<<<8192, 256, 0, stream>>>(zb, nullptr, (float*)d_out, gf, bfb);
}